// Round 7
// baseline (911.569 us; speedup 1.0000x reference)
//
#include <hip/hip_runtime.h>
#include <hip/hip_bf16.h>
#include <stdio.h>

// BNBQuantizedLinear: out = x @ dequant(w)^T + bias
// x [8192,4096] f32, w [11008,4096] f32 (group-128 affine fake-quant), out f32.
// Round 7: faithful m201-style 8-phase schedule. 256x256 tile, BK=64, dbuf=2
// (128 KiB LDS), 8 waves (2Mx4N, wave = 128x64 out). Per iter = 2 K-tiles =
// 8 phases; each phase = {quadrant ds_reads; 1 half-tile stage (2 gloads);
// [vmcnt]; barrier; setprio(1); 16 MFMA; setprio(0); barrier}. Counted
// vmcnt(4) ONLY at phases 4 and 8. Quadrant order (0,0),(1,0),(1,1),(0,1)
// -> 12/8/4/0 reads per phase, aq0 held across the half-iter.
// Stage stream (iter i): ph1:Bh0(2i+1) ph2:Bh1(2i+1) ph3:Ah0(2i+2)
// ph4:Ah1(2i+2) ph5:Bh0(2i+2) ph6:Bh1(2i+2) ph7:Ah0(2i+3) ph8:Ah1(2i+3).
// Ledger: A-halves of a buf are last read at ph2-top (qm0@ph1, qm1@ph2) ->
// free after ph2-end barrier -> staged ph3/ph4. B-halves last read ph3-top
// (qn0@ph1, qn1@ph3) -> staged ph5/ph6. VM4@ph4 keeps newest 4 loads
// (Ah(2i+2)) and drains Bh(2i+1)+Ah(2i+1) which ph5 reads. VM4@ph8 keeps
// Ah(2i+3), drains Ah/Bh(2i+2) which next ph1 reads. Swizzle: 8 16B-slots/row,
// slot' = slot ^ (row&7), applied on global source (linear gload_lds dest,
// rule 21) and on ds_read address -> even 8-lane/bank-quad spread (0-conflict
// criterion verified rounds 2-6).

typedef unsigned short u16;
typedef __attribute__((ext_vector_type(8))) short short8;
typedef __attribute__((ext_vector_type(8))) unsigned short ushort8;
typedef __attribute__((ext_vector_type(4))) float f32x4;

constexpr int Mdim = 8192;
constexpr int Ndim = 11008;
constexpr int Kdim = 4096;

#define BK 64
#define TILE16K 16384       // elems per K-tile buffer: 256 rows * 64 cols

__device__ __forceinline__ u16 f2bf(float f) {
  union { float f; unsigned u; } c; c.f = f;
  unsigned r = c.u + 0x7FFFu + ((c.u >> 16) & 1u);  // RTNE
  return (u16)(r >> 16);
}

// ---------------- kernel 1: group-dequant weight -> bf16 ----------------
__global__ __launch_bounds__(256) void k_dequant_w(const float* __restrict__ w,
                                                   u16* __restrict__ wb) {
  const int lane = threadIdx.x & 63;
  const long g = (long)blockIdx.x * 4 + (threadIdx.x >> 6);
  const long base = g * 128 + lane * 2;
  const float2 v = *(const float2*)(w + base);
  float mn = fminf(v.x, v.y), mx = fmaxf(v.x, v.y);
#pragma unroll
  for (int off = 32; off > 0; off >>= 1) {
    mn = fminf(mn, __shfl_xor(mn, off));
    mx = fmaxf(mx, __shfl_xor(mx, off));
  }
  const float scale = (mx - mn) / 15.0f;
  const float zp = -mn / scale;
  const u16 o0 = f2bf((v.x - zp) * scale);
  const u16 o1 = f2bf((v.y - zp) * scale);
  *(unsigned*)(wb + base) = (unsigned)o0 | ((unsigned)o1 << 16);
}

// ---------------- kernel 2: x f32 -> bf16 ----------------
__global__ __launch_bounds__(256) void k_cvt_x(const float* __restrict__ x,
                                               u16* __restrict__ xb) {
  const long i = ((long)blockIdx.x * 256 + threadIdx.x) * 8;
  const float4 v0 = *(const float4*)(x + i);
  const float4 v1 = *(const float4*)(x + i + 4);
  ushort8 o;
  o[0] = f2bf(v0.x); o[1] = f2bf(v0.y); o[2] = f2bf(v0.z); o[3] = f2bf(v0.w);
  o[4] = f2bf(v1.x); o[5] = f2bf(v1.y); o[6] = f2bf(v1.z); o[7] = f2bf(v1.w);
  *(ushort8*)(xb + i) = o;
}

// ---------------- kernel 3: 8-phase 256x256 bf16 GEMM ----------------
__device__ __forceinline__ void async_ld16(const u16* g, u16* l) {
  __builtin_amdgcn_global_load_lds(
      (const __attribute__((address_space(1))) void*)g,
      (__attribute__((address_space(3))) void*)l, 16, 0, 0);
}

__global__ __launch_bounds__(512, 2) void k_gemm(const u16* __restrict__ A,
                                                 const u16* __restrict__ B,
                                                 const float* __restrict__ bias,
                                                 float* __restrict__ C) {
  __shared__ u16 As[2 * TILE16K];   // 64 KB: dbuf of A K-tiles [256][64]
  __shared__ u16 Bs[2 * TILE16K];   // 64 KB

  const int t = threadIdx.x;
  const int wave = t >> 6;        // 0..7
  const int lane = t & 63;
  const int wm = wave >> 2;       // 2(M) x 4(N); wave owns 128x64 out
  const int wn = wave & 3;
  const int r  = lane & 15;
  const int kg = lane >> 4;
  // swizzled 16B-slot byte offsets for k-step 0/1 (slot = ks*4+kg, XOR row&7=r&7)
  const int sw0 = ((kg)     ^ (r & 7)) * 8;   // elems
  const int sw1 = ((4 + kg) ^ (r & 7)) * 8;

  // bijective XCD swizzle: 1376 workgroups = 8 XCDs x 172
  const int bid = blockIdx.x;
  const int wg = (bid & 7) * 172 + (bid >> 3);
  const int by = wg / 43;
  const int bx = wg % 43;
  const long bm0 = (long)by * 256;
  const long bn0 = (long)bx * 256;

  // staging: one issue = 512 thr x 16B = 8 KB = 64 rows x 64 cols.
  // thread t: row = t>>3, LDS slot = t&7 (linear dest); global slot pre-XOR'd.
  const int s_row  = t >> 3;                      // 0..63
  const int s_slot = (t & 7) ^ ((t >> 3) & 7);    // source pre-swizzle
  const u16* a_src = A + (bm0 + s_row) * Kdim + s_slot * 8;
  const u16* b_src = B + (bn0 + s_row) * Kdim + s_slot * 8;
  const int st_off = wave * 512;  // per-wave uniform LDS base within an issue

  const int a_base = (wm * 128 + r) * 64;   // elems within a K-tile buffer
  const int b_base = (wn * 64  + r) * 64;

  f32x4 acc[8][4] = {};
  short8 aq0[4][2], aq1[4][2], bq0[2][2], bq1[2][2];

#define STG_A(D, H, GQ) do {                                      \
    u16* l_ = As + (D) * TILE16K + (H) * 8192 + st_off;           \
    const u16* g_ = (GQ) + (size_t)((H) * 128) * Kdim;            \
    async_ld16(g_, l_);                                           \
    async_ld16(g_ + (size_t)64 * Kdim, l_ + 4096);                \
  } while (0)
#define STG_B(D, H, GQ) do {                                      \
    u16* l_ = Bs + (D) * TILE16K + (H) * 8192 + st_off;           \
    const u16* g_ = (GQ) + (size_t)((H) * 128) * Kdim;            \
    async_ld16(g_, l_);                                           \
    async_ld16(g_ + (size_t)64 * Kdim, l_ + 4096);                \
  } while (0)

#define READ_A(DST, D, QM) do {                                   \
    const u16* p_ = As + (D) * TILE16K + a_base + (QM) * 4096;    \
    _Pragma("unroll")                                             \
    for (int m2 = 0; m2 < 4; ++m2) {                              \
      DST[m2][0] = *(const short8*)&p_[m2 * 1024 + sw0];          \
      DST[m2][1] = *(const short8*)&p_[m2 * 1024 + sw1];          \
    }                                                             \
  } while (0)
#define READ_B(DST, D, QN) do {                                   \
    const u16* p_ = Bs + (D) * TILE16K + b_base + (QN) * 2048;    \
    _Pragma("unroll")                                             \
    for (int n2 = 0; n2 < 2; ++n2) {                              \
      DST[n2][0] = *(const short8*)&p_[n2 * 1024 + sw0];          \
      DST[n2][1] = *(const short8*)&p_[n2 * 1024 + sw1];          \
    }                                                             \
  } while (0)

#define MFMA_Q(AQ, BQ, QM, QN) do {                               \
    __builtin_amdgcn_s_setprio(1);                                \
    _Pragma("unroll")                                             \
    for (int ks = 0; ks < 2; ++ks)                                \
      _Pragma("unroll")                                           \
      for (int m2 = 0; m2 < 4; ++m2)                              \
        _Pragma("unroll")                                         \
        for (int n2 = 0; n2 < 2; ++n2)                            \
          acc[(QM)*4+m2][(QN)*2+n2] = __builtin_amdgcn_mfma_f32_16x16x32_bf16( \
              AQ[m2][ks], BQ[n2][ks], acc[(QM)*4+m2][(QN)*2+n2], 0, 0, 0);     \
    __builtin_amdgcn_s_setprio(0);                                \
  } while (0)

#define BAR __builtin_amdgcn_s_barrier()
#define VM4 asm volatile("s_waitcnt vmcnt(4)" ::: "memory")
#define VM0 asm volatile("s_waitcnt vmcnt(0)" ::: "memory")
#define VMNONE (void)0

#define ITER(GB1, GA2, GB2, GA3, S12, S38, VMA, VMB) do {         \
    /* ph1: quadrant (0,0) */                                     \
    READ_A(aq0, 0, 0); READ_B(bq0, 0, 0);                         \
    if (S12) STG_B(1, 0, GB1);                                    \
    BAR; MFMA_Q(aq0, bq0, 0, 0); BAR;                             \
    /* ph2: (1,0) */                                              \
    READ_A(aq1, 0, 1);                                            \
    if (S12) STG_B(1, 1, GB1);                                    \
    BAR; MFMA_Q(aq1, bq0, 1, 0); BAR;                             \
    /* ph3: (1,1) */                                              \
    READ_B(bq1, 0, 1);                                            \
    if (S38) STG_A(0, 0, GA2);                                    \
    BAR; MFMA_Q(aq1, bq1, 1, 1); BAR;                             \
    /* ph4: (0,1), no reads */                                    \
    if (S38) STG_A(0, 1, GA2);                                    \
    VMA; BAR; MFMA_Q(aq0, bq1, 0, 1); BAR;                        \
    /* ph5: (0,0) of odd tile */                                  \
    READ_A(aq0, 1, 0); READ_B(bq0, 1, 0);                         \
    if (S38) STG_B(0, 0, GB2);                                    \
    BAR; MFMA_Q(aq0, bq0, 0, 0); BAR;                             \
    /* ph6: (1,0) */                                              \
    READ_A(aq1, 1, 1);                                            \
    if (S38) STG_B(0, 1, GB2);                                    \
    BAR; MFMA_Q(aq1, bq0, 1, 0); BAR;                             \
    /* ph7: (1,1) */                                              \
    READ_B(bq1, 1, 1);                                            \
    if (S38) STG_A(1, 0, GA3);                                    \
    BAR; MFMA_Q(aq1, bq1, 1, 1); BAR;                             \
    /* ph8: (0,1) */                                              \
    if (S38) STG_A(1, 1, GA3);                                    \
    VMB; BAR; MFMA_Q(aq0, bq1, 0, 1); BAR;                        \
  } while (0)

  // prologue: tile 0 (all 4 halves -> dbuf0), Ah(1) -> dbuf1; drain tile 0.
  STG_A(0, 0, a_src);
  STG_A(0, 1, a_src);
  STG_B(0, 0, b_src);
  STG_B(0, 1, b_src);
  STG_A(1, 0, a_src + 64);
  STG_A(1, 1, a_src + 64);
  VM4;                     // keep Ah(1)'s 4 loads, drain tile 0's 8
  BAR;

  // main: iters 0..30 (tiles 0..61), tail iter 31 (tiles 62,63)
  for (int i = 0; i < 31; ++i) {
    const u16* gb1 = b_src + (size_t)(2 * i + 1) * 64;
    const u16* ga2 = a_src + (size_t)(2 * i + 2) * 64;
    const u16* gb2 = b_src + (size_t)(2 * i + 2) * 64;
    const u16* ga3 = a_src + (size_t)(2 * i + 3) * 64;
    ITER(gb1, ga2, gb2, ga3, 1, 1, VM4, VM4);
  }
  {
    const u16* gb1 = b_src + (size_t)63 * 64;
    ITER(gb1, a_src, b_src, a_src, 1, 0, VM0, VMNONE);
  }

  // epilogue: C/D layout col = lane&15, row = (lane>>4)*4 + j
#pragma unroll
  for (int nf = 0; nf < 4; ++nf) {
    const long col = bn0 + wn * 64 + nf * 16 + r;
    const float bv = bias[col];
#pragma unroll
    for (int mf = 0; mf < 8; ++mf) {
      const long row0 = bm0 + wm * 128 + mf * 16 + kg * 4;
#pragma unroll
      for (int j = 0; j < 4; ++j)
        C[(row0 + j) * Ndim + col] = acc[mf][nf][j] + bv;
    }
  }
}

extern "C" void kernel_launch(void* const* d_in, const int* in_sizes, int n_in,
                              void* d_out, int out_size, void* d_ws, size_t ws_size,
                              hipStream_t stream) {
  const float* x    = (const float*)d_in[0];
  const float* w    = (const float*)d_in[1];
  const float* bias = (const float*)d_in[2];
  float* out = (float*)d_out;

  const size_t xb_elems = (size_t)Mdim * Kdim;
  const size_t wb_elems = (size_t)Ndim * Kdim;
  const size_t need = (xb_elems + wb_elems) * sizeof(u16);
  if (ws_size < need) {
    fprintf(stderr, "kernel_launch: ws too small (%zu < %zu)\n", ws_size, need);
    return;
  }
  u16* xb = (u16*)d_ws;
  u16* wb = xb + xb_elems;

  k_dequant_w<<<(int)(wb_elems / 128 / 4), 256, 0, stream>>>(w, wb);
  k_cvt_x<<<(int)(xb_elems / (8 * 256)), 256, 0, stream>>>(x, xb);

  // grid: 43 N-tiles x 32 M-tiles = 1376 blocks (divisible by 8 XCDs)
  k_gemm<<<(Ndim / 256) * (Mdim / 256), 512, 0, stream>>>(xb, wb, bias, out);
}